// Round 9
// baseline (1380.915 us; speedup 1.0000x reference)
//
#include <hip/hip_runtime.h>

typedef __bf16 bf16;
typedef bf16 bf16x4 __attribute__((ext_vector_type(4)));
typedef bf16 bf16x8 __attribute__((ext_vector_type(8)));
typedef float f32x4 __attribute__((ext_vector_type(4)));
typedef unsigned long u64x2 __attribute__((ext_vector_type(2)));

#define AS1 __attribute__((address_space(1)))
#define AS3 __attribute__((address_space(3)))

#define B_ 2048
#define T_ 80
#define E_ 100
#define H_ 512
#define TC_ 16              // time-chunk
#define NC_ (T_ / TC_)      // 5 chunks
#define ROWS_ 16            // batch rows per rnn block

// SEQ is TIME-MAJOR: seq[(t*B_ + b)*H_ + h]
// U fp8 A-OPERAND layout (operand-swapped rnn: D = (h@U)^T = mfma(A=U^T, B=h)):
//   hidden-tile ht (16 cols of U, i.e. 16 output hiddens), kk-pair p ->
//   1024B block at (ht*8+p)*1024; byte[lane*16 + half*8 + j] =
//     U[k=(2p+half)*32 + (lane>>4)*8 + j][ht*16 + (lane&15)] * 2^6
//   (A-frag map: m=lane&15 (hidden), k=(lane>>4)*8+j — same map the pre-swap
//    code validated; wave ht-pair stream = 16KB contiguous dwordx4 loads.)

__device__ __forceinline__ float fast_tanh(float x) {
  float e = exp2f(x * 2.8853900817779268f);  // e^{2x}
  return 1.f - 2.f * __builtin_amdgcn_rcpf(e + 1.f);
}

__device__ __forceinline__ long pack_fp8x8(const float* f) {
  int w0 = __builtin_amdgcn_cvt_pk_fp8_f32(f[0], f[1], 0, false);
  w0 = __builtin_amdgcn_cvt_pk_fp8_f32(f[2], f[3], w0, true);
  int w1 = __builtin_amdgcn_cvt_pk_fp8_f32(f[4], f[5], 0, false);
  w1 = __builtin_amdgcn_cvt_pk_fp8_f32(f[6], f[7], w1, true);
  return (long)(((unsigned long)(unsigned)w1 << 32) | (unsigned)w0);
}

// dst[n*Kp + k] = k<K ? src[k*N + n] : 0
__global__ void convert_weight(const float* __restrict__ src, bf16* __restrict__ dst,
                               int K, int Kp, int N) {
  int idx = blockIdx.x * 256 + threadIdx.x;
  if (idx >= N * Kp) return;
  int n = idx / Kp, k = idx - n * Kp;
  float v = (k < K) ? src[(long)k * N + n] : 0.f;
  dst[idx] = (bf16)v;
}

// U[512x512] fp32 -> fp8 e4m3 * 2^6, A-operand layout above. 32768 threads.
__global__ void convert_u_fp8(const float* __restrict__ src, unsigned char* __restrict__ dst) {
  int idx = blockIdx.x * 256 + threadIdx.x;
  int half = idx & 1, lane = (idx >> 1) & 63, p = (idx >> 7) & 7, ht = idx >> 10;
  int q = lane >> 4;
  int k0 = (2 * p + half) * 32 + q * 8;
  int n = ht * 16 + (lane & 15);
  float f[8];
#pragma unroll
  for (int j = 0; j < 8; j++) f[j] = src[(long)(k0 + j) * H_ + n] * 64.f;
  *(long*)(dst + (long)(ht * 8 + p) * 1024 + lane * 16 + half * 8) = pack_fp8x8(f);
}

// C[128-row tile] = A @ Bt^T; A pre-offset to chunk start. Grid (TC_*B_/128, 4), 256 thr.
__global__ __launch_bounds__(256) void gemm_bf16(
    const bf16* __restrict__ A, const bf16* __restrict__ Bt, bf16* __restrict__ C, int K) {
  __shared__ bf16 As[128 * 32];
  __shared__ bf16 Bs[128 * 32];
  const int tid = threadIdx.x;
  const int wave = tid >> 6, lane = tid & 63;
  const int l = lane & 15, q = lane >> 4;
  const long m0 = (long)blockIdx.x * 128;
  const int n0 = blockIdx.y * 128;
  const int wm = (wave >> 1) * 64, wn = (wave & 1) * 64;

  f32x4 acc[4][4] = {};

  const int e0 = tid, e1 = 256 + tid;
  const int r0 = e0 >> 2, c0 = e0 & 3;
  const int r1 = e1 >> 2, c1 = e1 & 3;
  const int s0 = c0 ^ (r0 & 3) ^ ((r0 >> 2) & 3);
  const int s1 = c1 ^ (r1 & 3) ^ ((r1 >> 2) & 3);
  const int swr = q ^ (l & 3) ^ ((l >> 2) & 3);

  const bf16* A0 = A + (m0 + r0) * K + s0 * 8;
  const bf16* A1 = A + (m0 + r1) * K + s1 * 8;
  const bf16* B0 = Bt + (long)(n0 + r0) * K + s0 * 8;
  const bf16* B1 = Bt + (long)(n0 + r1) * K + s1 * 8;
  bf16* AsW0 = As + (wave * 64) * 8;
  bf16* AsW1 = As + (256 + wave * 64) * 8;
  bf16* BsW0 = Bs + (wave * 64) * 8;
  bf16* BsW1 = Bs + (256 + wave * 64) * 8;

  for (int k0 = 0; k0 < K; k0 += 32) {
    __builtin_amdgcn_global_load_lds((const AS1 void*)(A0 + k0), (AS3 void*)AsW0, 16, 0, 0);
    __builtin_amdgcn_global_load_lds((const AS1 void*)(A1 + k0), (AS3 void*)AsW1, 16, 0, 0);
    __builtin_amdgcn_global_load_lds((const AS1 void*)(B0 + k0), (AS3 void*)BsW0, 16, 0, 0);
    __builtin_amdgcn_global_load_lds((const AS1 void*)(B1 + k0), (AS3 void*)BsW1, 16, 0, 0);
    __syncthreads();
    bf16x8 af[4], bfm[4];
#pragma unroll
    for (int i = 0; i < 4; i++) {
      af[i]  = *(const bf16x8*)(As + (wm + i * 16 + l) * 32 + swr * 8);
      bfm[i] = *(const bf16x8*)(Bs + (wn + i * 16 + l) * 32 + swr * 8);
    }
#pragma unroll
    for (int i = 0; i < 4; i++)
#pragma unroll
      for (int j = 0; j < 4; j++)
        acc[i][j] = __builtin_amdgcn_mfma_f32_16x16x32_bf16(af[i], bfm[j], acc[i][j], 0, 0, 0);
    __syncthreads();
  }
#pragma unroll
  for (int i = 0; i < 4; i++)
#pragma unroll
    for (int j = 0; j < 4; j++)
#pragma unroll
      for (int r = 0; r < 4; r++)
        C[(m0 + wm + i * 16 + q * 4 + r) * (long)H_ + n0 + wn + j * 16 + l] =
            (bf16)acc[i][j][r];
}

// Layer-1 GEMM with fused embedding gather: C = emb[tokens] @ W1 (K padded to 128).
__global__ __launch_bounds__(256) void gemm1_embed(
    const int* __restrict__ tokens, const float* __restrict__ emb,
    const bf16* __restrict__ Bt, bf16* __restrict__ xwc, int t0) {
  __shared__ bf16 As[128 * 32];
  __shared__ bf16 Bs[128 * 32];
  __shared__ int stok[128];
  const int tid = threadIdx.x;
  const int wave = tid >> 6, lane = tid & 63;
  const int l = lane & 15, q = lane >> 4;
  const int trow = blockIdx.x >> 4;
  const int b0 = (blockIdx.x & 15) * 128;
  const int t = t0 + trow;
  const int n0 = blockIdx.y * 128;
  const int wm = (wave >> 1) * 64, wn = (wave & 1) * 64;
  const int K = 128;

  if (tid < 128) stok[tid] = tokens[(b0 + tid) * T_ + t];
  __syncthreads();

  f32x4 acc[4][4] = {};

  const int e0 = tid, e1 = 256 + tid;
  const int r0 = e0 >> 2, c0 = e0 & 3;
  const int r1 = e1 >> 2, c1 = e1 & 3;
  const int s0 = c0 ^ (r0 & 3) ^ ((r0 >> 2) & 3);
  const int s1 = c1 ^ (r1 & 3) ^ ((r1 >> 2) & 3);
  const int swr = q ^ (l & 3) ^ ((l >> 2) & 3);

  const bf16* B0 = Bt + (long)(n0 + r0) * K + s0 * 8;
  const bf16* B1 = Bt + (long)(n0 + r1) * K + s1 * 8;
  bf16* BsW0 = Bs + (wave * 64) * 8;
  bf16* BsW1 = Bs + (256 + wave * 64) * 8;

  const int ar = tid >> 1, hh = tid & 1;
  const int asw = (ar & 3) ^ ((ar >> 2) & 3);
  const float* er = emb + (long)stok[ar] * E_;

  for (int k0 = 0; k0 < K; k0 += 32) {
    __builtin_amdgcn_global_load_lds((const AS1 void*)(B0 + k0), (AS3 void*)BsW0, 16, 0, 0);
    __builtin_amdgcn_global_load_lds((const AS1 void*)(B1 + k0), (AS3 void*)BsW1, 16, 0, 0);
    bf16x8 v[2];
#pragma unroll
    for (int cch = 0; cch < 2; cch++) {
      int kb = k0 + hh * 16 + cch * 8;
#pragma unroll
      for (int j = 0; j < 8; j++) {
        int k = kb + j;
        v[cch][j] = (bf16)((k < E_) ? er[k] : 0.f);
      }
    }
    *(bf16x8*)(As + ar * 32 + ((2 * hh + 0) ^ asw) * 8) = v[0];
    *(bf16x8*)(As + ar * 32 + ((2 * hh + 1) ^ asw) * 8) = v[1];
    __syncthreads();
    bf16x8 af[4], bfm[4];
#pragma unroll
    for (int i = 0; i < 4; i++) {
      af[i]  = *(const bf16x8*)(As + (wm + i * 16 + l) * 32 + swr * 8);
      bfm[i] = *(const bf16x8*)(Bs + (wn + i * 16 + l) * 32 + swr * 8);
    }
#pragma unroll
    for (int i = 0; i < 4; i++)
#pragma unroll
      for (int j = 0; j < 4; j++)
        acc[i][j] = __builtin_amdgcn_mfma_f32_16x16x32_bf16(af[i], bfm[j], acc[i][j], 0, 0, 0);
    __syncthreads();
  }
  bf16* C = xwc + ((long)trow * B_ + b0) * H_;
#pragma unroll
  for (int i = 0; i < 4; i++)
#pragma unroll
    for (int j = 0; j < 4; j++)
#pragma unroll
      for (int r = 0; r < 4; r++)
        C[(long)(wm + i * 16 + q * 4 + r) * H_ + n0 + wn + j * 16 + l] =
            (bf16)acc[i][j][r];
}

// Recurrent chunk, OPERAND-SWAPPED: 128 blocks x 1024 thr (16 waves = 4/SIMD);
// block = 16 batch rows; wave owns 2 hidden-tiles (32 hiddens) x 16 batch.
// D = (h@U)^T: A = U^T fp8 from L2 (contiguous dwordx4, dist-3 pipeline),
// B = h fp8 in LDS (b64 reads, shared across the wave's 2 tiles).
// Epilogue per thread per tile: 1 b64 xw read, 1 b32 fp8-h write, 1 b64 hstg
// write (all contiguous-4 in hidden) -> LDS wave-ops 640->352 per step/CU.
__global__ __launch_bounds__(1024) void rnn_chunk(
    const bf16* __restrict__ xwc, const unsigned char* __restrict__ U8,
    const float* __restrict__ bias, bf16* __restrict__ seq, int t0, int first) {
  __shared__ long hls8_[2 * ROWS_ * 65];      // 2 x (16 batch x 520 B) fp8 h
  __shared__ bf16 xws[4 * ROWS_ * 520];       // 4-buf xw staging [batch][hidden]
  __shared__ bf16 hstg[2 * ROWS_ * 520];      // 2-buf bf16 h staging [batch][hidden]
  char* hls8 = (char*)hls8_;
  const int tid = threadIdx.x;
  const int wave = tid >> 6, lane = tid & 63;
  const int l = lane & 15, q = lane >> 4;
  const int b0 = blockIdx.x * ROWS_;

  // init h_{t0-1} into buffer 0: wave handles batch row `wave` (scale 2^4, fp8)
  {
    long pk = 0;
    if (!first) {
      const bf16* hsrc = seq + ((long)(t0 - 1) * B_ + b0 + wave) * H_;
      bf16x8 v = *(const bf16x8*)(hsrc + lane * 8);
      float f[8];
#pragma unroll
      for (int j = 0; j < 8; j++) f[j] = (float)v[j] * 16.f;
      pk = pack_fp8x8(f);
    }
    *(long*)(hls8 + wave * 520 + lane * 8) = pk;
  }

  // bias, indexed by hidden = (wave*2+nt)*16 + q*4 + r
  float bb[2][4];
#pragma unroll
  for (int nt = 0; nt < 2; nt++)
#pragma unroll
    for (int r = 0; r < 4; r++)
      bb[nt][r] = bias[(wave * 2 + nt) * 16 + q * 4 + r];

  // async xw prefetch: wave issues batch row `wave`; row = 1024B contiguous
  auto prefetch = [&](int tl) {
    int buf = tl & 3;
    __builtin_amdgcn_global_load_lds(
        (const AS1 void*)(xwc + ((long)tl * B_ + b0 + wave) * H_ + lane * 8),
        (AS3 void*)(xws + (buf * ROWS_ + wave) * 520), 16, 0, 0);
  };

  prefetch(0);
  prefetch(1);
  __syncthreads();  // xws bufs 0,1 ready; hls8[0] visible

  // wave's U^T A-operand stream: hidden-tiles 2*wave, 2*wave+1 (8KB each)
  const unsigned char* Ub = U8 + (long)(wave * 2) * 8192 + lane * 16;

  for (int tl = 0; tl < TC_; tl++) {
    if (tl + 2 < TC_) prefetch(tl + 2);

    const char* hb8 = hls8 + ((tl & 1) * ROWS_ + l) * 520 + q * 8;
    f32x4 acc[2] = {};
    // (h@U)^T: A = U^T frags (dist-3 reg pipeline), B = h frags from LDS
    u64x2 bfr[3][2];
#pragma unroll
    for (int d = 0; d < 3; d++)
#pragma unroll
      for (int nt = 0; nt < 2; nt++)
        bfr[d][nt] = *(const u64x2*)(Ub + nt * 8192 + d * 1024);
#pragma unroll
    for (int kk2 = 0; kk2 < 8; kk2++) {
      const int cur = kk2 % 3;
      long h0 = *(const long*)(hb8 + kk2 * 64);        // B frag, kk = 2*kk2
      long h1 = *(const long*)(hb8 + kk2 * 64 + 32);   // B frag, kk = 2*kk2+1
#pragma unroll
      for (int nt = 0; nt < 2; nt++)
        acc[nt] = __builtin_amdgcn_mfma_f32_16x16x32_fp8_fp8((long)bfr[cur][nt].x, h0,
                                                             acc[nt], 0, 0, 0);
#pragma unroll
      for (int nt = 0; nt < 2; nt++)
        acc[nt] = __builtin_amdgcn_mfma_f32_16x16x32_fp8_fp8((long)bfr[cur][nt].y, h1,
                                                             acc[nt], 0, 0, 0);
      if (kk2 < 5) {
#pragma unroll
        for (int nt = 0; nt < 2; nt++)
          bfr[cur][nt] = *(const u64x2*)(Ub + nt * 8192 + (kk2 + 3) * 1024);
      }
    }
    // h = tanh(xw + b + acc * 2^-10); D: col=batch(l), row=hidden(q*4+r)
    const bf16* xrb = xws + ((tl & 3) * ROWS_ + l) * 520;
    float hv[2][4];
#pragma unroll
    for (int nt = 0; nt < 2; nt++) {
      int hoff = (wave * 2 + nt) * 16 + q * 4;
      bf16x4 xv = *(const bf16x4*)(xrb + hoff);
#pragma unroll
      for (int r = 0; r < 4; r++)
        hv[nt][r] = fast_tanh((float)xv[r] + bb[nt][r] + acc[nt][r] * 0.0009765625f);
    }

    // write h_t: fp8 (b32, packed x4) -> hls8[(tl+1)&1]; bf16 (b64) -> hstg[tl&1]
#pragma unroll
    for (int nt = 0; nt < 2; nt++) {
      int hoff = (wave * 2 + nt) * 16 + q * 4;
      unsigned pw = (unsigned)__builtin_amdgcn_cvt_pk_fp8_f32(
          hv[nt][0] * 16.f, hv[nt][1] * 16.f, 0, false);
      pw = (unsigned)__builtin_amdgcn_cvt_pk_fp8_f32(
          hv[nt][2] * 16.f, hv[nt][3] * 16.f, (int)pw, true);
      *(unsigned*)(hls8 + (((tl + 1) & 1) * ROWS_ + l) * 520 + hoff) = pw;
      bf16x4 hb;
#pragma unroll
      for (int r = 0; r < 4; r++) hb[r] = (bf16)hv[nt][r];
      *(bf16x4*)(hstg + ((tl & 1) * ROWS_ + l) * 520 + hoff) = hb;
    }

    // coalesced seq store of step tl-1 from the retired staging buffer
    if (tl > 0) {
      bf16* sp = seq + ((long)(t0 + tl - 1) * B_ + b0 + wave) * H_;
      *(bf16x8*)(sp + lane * 8) =
          *(const bf16x8*)(hstg + (((tl - 1) & 1) * ROWS_ + wave) * 520 + lane * 8);
    }

    __syncthreads();  // single barrier per step
  }
  {
    bf16* sp = seq + ((long)(t0 + TC_ - 1) * B_ + b0 + wave) * H_;
    *(bf16x8*)(sp + lane * 8) =
        *(const bf16x8*)(hstg + (((TC_ - 1) & 1) * ROWS_ + wave) * 520 + lane * 8);
  }
}

// out[b] = sigmoid(dot(seq[(T-1)*B + b, :], Wo) + bo); one wave per row
__global__ __launch_bounds__(256) void head_kernel(
    const bf16* __restrict__ seq, const float* __restrict__ Wo,
    const float* __restrict__ bo, float* __restrict__ out) {
  int wave = threadIdx.x >> 6, lane = threadIdx.x & 63;
  int row = blockIdx.x * 4 + wave;
  const bf16* p = seq + ((long)(T_ - 1) * B_ + row) * H_ + lane * 8;
  bf16x8 v = *(const bf16x8*)p;
  float s = 0.f;
#pragma unroll
  for (int i = 0; i < 8; i++) s += (float)v[i] * Wo[lane * 8 + i];
#pragma unroll
  for (int off = 32; off; off >>= 1) s += __shfl_down(s, off, 64);
  if (lane == 0) {
    float x = s + bo[0];
    out[row] = 1.f / (1.f + exp2f(-x * 1.44269504088896f));
  }
}

extern "C" void kernel_launch(void* const* d_in, const int* in_sizes, int n_in,
                              void* d_out, int out_size, void* d_ws, size_t ws_size,
                              hipStream_t stream) {
  (void)in_sizes; (void)n_in; (void)out_size; (void)ws_size;
  const int*   tokens = (const int*)d_in[0];
  const float* emb = (const float*)d_in[1];
  const float* W1 = (const float*)d_in[2];
  const float* U1 = (const float*)d_in[3];
  const float* b1 = (const float*)d_in[4];
  const float* W2 = (const float*)d_in[5];
  const float* U2 = (const float*)d_in[6];
  const float* b2 = (const float*)d_in[7];
  const float* W3 = (const float*)d_in[8];
  const float* U3 = (const float*)d_in[9];
  const float* b3 = (const float*)d_in[10];
  const float* W4 = (const float*)d_in[11];
  const float* U4 = (const float*)d_in[12];
  const float* b4 = (const float*)d_in[13];
  const float* Wo = (const float*)d_in[14];
  const float* bo = (const float*)d_in[15];
  float* out = (float*)d_out;

  char* w = (char*)d_ws;
  const size_t SEQ_BYTES = (size_t)T_ * B_ * H_ * 2;   // 160 MB
  const size_t XWC_BYTES = (size_t)TC_ * B_ * H_ * 2;  // 32 MB
  bf16* SEQ = (bf16*)w;
  bf16* XWC = (bf16*)(w + SEQ_BYTES);
  bf16* W1t = (bf16*)(w + SEQ_BYTES + XWC_BYTES);
  bf16* W2t = W1t + 512 * 128;
  bf16* W3t = W2t + 512 * 512;
  bf16* W4t = W3t + 512 * 512;
  unsigned char* U1p = (unsigned char*)(W4t + 512 * 512);
  unsigned char* U2p = U1p + 512 * 512;
  unsigned char* U3p = U2p + 512 * 512;
  unsigned char* U4p = U3p + 512 * 512;

  convert_weight<<<(512 * 128) / 256, 256, 0, stream>>>(W1, W1t, 100, 128, 512);
  convert_weight<<<(512 * 512) / 256, 256, 0, stream>>>(W2, W2t, 512, 512, 512);
  convert_weight<<<(512 * 512) / 256, 256, 0, stream>>>(W3, W3t, 512, 512, 512);
  convert_weight<<<(512 * 512) / 256, 256, 0, stream>>>(W4, W4t, 512, 512, 512);
  convert_u_fp8<<<128, 256, 0, stream>>>(U1, U1p);
  convert_u_fp8<<<128, 256, 0, stream>>>(U2, U2p);
  convert_u_fp8<<<128, 256, 0, stream>>>(U3, U3p);
  convert_u_fp8<<<128, 256, 0, stream>>>(U4, U4p);

  const bf16* Wt[4] = {W1t, W2t, W3t, W4t};
  const unsigned char* Up[4] = {U1p, U2p, U3p, U4p};
  const float* bs[4] = {b1, b2, b3, b4};

  for (int layer = 0; layer < 4; layer++) {
    for (int c = 0; c < NC_; c++) {
      if (layer == 0)
        gemm1_embed<<<dim3(TC_ * 16, 4), 256, 0, stream>>>(tokens, emb, W1t, XWC, c * TC_);
      else
        gemm_bf16<<<dim3(TC_ * B_ / 128, 4), 256, 0, stream>>>(
            SEQ + (size_t)c * TC_ * B_ * H_, Wt[layer], XWC, H_);
      rnn_chunk<<<B_ / ROWS_, 1024, 0, stream>>>(XWC, Up[layer], bs[layer], SEQ, c * TC_, c == 0);
    }
  }

  head_kernel<<<B_ / 4, 256, 0, stream>>>(SEQ, Wo, bo, out);
}